// Round 2
// baseline (535.773 us; speedup 1.0000x reference)
//
#include <hip/hip_runtime.h>
#include <cmath>

// loss_b = max_c hinge((M @ d_c).xy / (M @ d_c).z / [W,H]),  M = Pr_b @ Rv_bᵀ,
// d_c = K⁻¹ @ corner_c (host constants). Pr_b = real_projection_t[b, 6] — only
// 36 B of each 432 B record is needed. Per 4 records (1728 B) those windows sit
// in exactly six 64 B sectors: {192, 640, 1024, 1088, 1472, 1536}. Each block
// stages its 256 records' sectors cooperatively (dense dwordx4, 4 lanes/sector)
// into LDS, then each thread reads its 9 floats from LDS.
//
// LDS layout: group g (4 records) -> 100 floats (96 data + 4 pad). Pad keeps
// float4 writes 16B-aligned (100*4 % 16 == 0) and breaks the 16-lane bank
// pileup a 96-stride would cause. Record j in group: float offset {6,18,46,74}.

__device__ __forceinline__ float record_loss(
    float qx, float qy, float qz, float qw, const float* __restrict__ P,
    float d0x, float d0y, float d1x, float d1y,
    float d2x, float d2y, float d3x, float d3y)
{
    float n  = sqrtf(qx*qx + qy*qy + qz*qz + qw*qw);
    float in_ = 1.0f / n;
    qx *= in_; qy *= in_; qz *= in_; qw *= in_;
    float r00 = 1.0f - 2.0f*(qy*qy + qz*qz);
    float r01 = 2.0f*(qx*qy - qz*qw);
    float r02 = 2.0f*(qx*qz + qy*qw);
    float r10 = 2.0f*(qx*qy + qz*qw);
    float r11 = 1.0f - 2.0f*(qx*qx + qz*qz);
    float r12 = 2.0f*(qy*qz - qx*qw);
    float r20 = 2.0f*(qx*qz - qy*qw);
    float r21 = 2.0f*(qy*qz + qx*qw);
    float r22 = 1.0f - 2.0f*(qx*qx + qy*qy);

    float P0=P[0],P1=P[1],P2=P[2],P3=P[3],P4=P[4],P5=P[5],P6=P[6],P7=P[7],P8=P[8];

    // M = Pr @ Rvᵀ
    float m00 = P0*r00 + P1*r01 + P2*r02;
    float m01 = P0*r10 + P1*r11 + P2*r12;
    float m02 = P0*r20 + P1*r21 + P2*r22;
    float m10 = P3*r00 + P4*r01 + P5*r02;
    float m11 = P3*r10 + P4*r11 + P5*r12;
    float m12 = P3*r20 + P4*r21 + P5*r22;
    float m20 = P6*r00 + P7*r01 + P8*r02;
    float m21 = P6*r10 + P7*r11 + P8*r12;
    float m22 = P6*r20 + P7*r21 + P8*r22;

    const float invW = 1.0f / 1920.0f, invH = 1.0f / 1080.0f;
    float best = -1e30f;
    float dxs[4] = {d0x, d1x, d2x, d3x};
    float dys[4] = {d0y, d1y, d2y, d3y};
    #pragma unroll
    for (int c = 0; c < 4; ++c) {
        float dx = dxs[c], dy = dys[c];
        float px = m00*dx + m01*dy + m02;
        float py = m10*dx + m11*dy + m12;
        float pz = m20*dx + m21*dy + m22;
        float rz = 1.0f / pz;
        float x  = px * rz * invW;
        float y  = py * rz * invH;
        float v  = fmaxf(0.0f, -x) + fmaxf(0.0f, x - 1.0f)
                 + fmaxf(0.0f, -y) + fmaxf(0.0f, y - 1.0f);
        best = fmaxf(best, v);
    }
    return best;
}

__global__ __launch_bounds__(256) void loss_kernel(
    const float* __restrict__ Vt,       // [B,4]
    const float* __restrict__ Prt,      // [B,12,3,3] row-major (108 floats/record)
    float* __restrict__ out,            // [1], zeroed
    int B,
    float d0x, float d0y, float d1x, float d1y,
    float d2x, float d2y, float d3x, float d3y)
{
    __shared__ float stage[64 * 100];   // 64 groups x (96 data + 4 pad) = 25.6 KB
    __shared__ float wsum[4];

    const int t = threadIdx.x;
    const long long R = (long long)blockIdx.x * 256;   // first record of block
    float loss = 0.0f;

    if (R + 256 <= (long long)B) {
        // ---- cooperative sector-exact staging: 1536 x 16B chunks ----
        const char* base = (const char*)Prt;
        const int secoff[6] = {192, 640, 1024, 1088, 1472, 1536};
        #pragma unroll
        for (int i = 0; i < 6; ++i) {
            int c   = i * 256 + t;       // chunk id 0..1535
            int g   = c / 24;            // group 0..63
            int rem = c - g * 24;
            int s   = rem >> 2;          // sector slot 0..5
            int q   = rem & 3;           // 16B quarter 0..3
            long long gaddr = (R + 4ll * g) * 432 + secoff[s] + q * 16;
            float4 v = *reinterpret_cast<const float4*>(base + gaddr);
            *reinterpret_cast<float4*>(stage + g * 100 + s * 16 + q * 4) = v;
        }
        // Vt (coalesced) while stage loads are in flight
        float4 q4 = *reinterpret_cast<const float4*>(Vt + 4 * (R + t));
        __syncthreads();

        const int g = t >> 2, j = t & 3;
        const int foff[4] = {6, 18, 46, 74};
        const float* P = stage + g * 100 + foff[j];
        loss = record_loss(q4.x, q4.y, q4.z, q4.w, P,
                           d0x, d0y, d1x, d1y, d2x, d2y, d3x, d3y);
    } else {
        // tail block (not hit for B % 256 == 0): direct gather path
        long long b = R + t;
        if (b < B) {
            float4 q4 = *reinterpret_cast<const float4*>(Vt + 4 * b);
            float Pl[9];
            const float* P = Prt + (size_t)b * 108 + 54;
            #pragma unroll
            for (int k = 0; k < 9; ++k) Pl[k] = P[k];
            loss = record_loss(q4.x, q4.y, q4.z, q4.w, Pl,
                               d0x, d0y, d1x, d1y, d2x, d2y, d3x, d3y);
        }
        __syncthreads();  // keep barrier wave-uniform with the fast path
    }

    // ---- reduction: wave shuffle -> LDS -> one atomic per block ----
    #pragma unroll
    for (int off = 32; off > 0; off >>= 1)
        loss += __shfl_down(loss, off, 64);
    int lane = t & 63;
    int wv   = t >> 6;
    if (lane == 0) wsum[wv] = loss;
    __syncthreads();
    if (t == 0) {
        float s = wsum[0] + wsum[1] + wsum[2] + wsum[3];
        atomicAdd(out, s);
    }
}

extern "C" void kernel_launch(void* const* d_in, const int* in_sizes, int n_in,
                              void* d_out, int out_size, void* d_ws, size_t ws_size,
                              hipStream_t stream) {
    const float* Vt  = (const float*)d_in[0];
    const float* Prt = (const float*)d_in[1];
    float* out = (float*)d_out;
    int B = in_sizes[0] / 4;

    const double fd = 0.5 * 1080.0 / tan(0.5 * 0.8);
    const float  f  = (float)fd;
    const float  cx = 0.5f * 1920.0f, cy = 0.5f * 1080.0f;
    const float  x0 = 192.0f, x1 = 1728.0f, y0 = 108.0f, y1 = 972.0f;
    float d0x = (x0 - cx) / f, d0y = (y0 - cy) / f;
    float d1x = (x0 - cx) / f, d1y = (y1 - cy) / f;
    float d2x = (x1 - cx) / f, d2y = (y0 - cy) / f;
    float d3x = (x1 - cx) / f, d3y = (y1 - cy) / f;

    hipMemsetAsync(d_out, 0, sizeof(float), stream);
    int threads = 256;
    int blocks  = (B + threads - 1) / threads;
    loss_kernel<<<blocks, threads, 0, stream>>>(Vt, Prt, out, B,
        d0x, d0y, d1x, d1y, d2x, d2y, d3x, d3y);
}